// Round 12
// baseline (2287.519 us; speedup 1.0000x reference)
//
#include <hip/hip_runtime.h>
#include <stdint.h>

// B=4,H=16,S=2048,D=64 fp32 SDPA with materialized attn_prob.
// r12 = r11 with ALL nontemporal hints removed (clean A/B on occupancy theory).
// Two-pass online softmax. Pass 1: QK^T (swapped MFMA) + running max/sum,
// mask cached as 64 bits/lane. Pass 2: recompute scores via MFMA (K L2-hot),
// write prob, PV. Spill-free at <=128 regs -> 2 blocks/CU.
#define SEQ 2048
#define DIM 64
#define QBLK 16
#define NWAVE 8
#define KPW 256
#define NCT 16
#define NCHUNK 8
#define THREADS 512
#define SCALE 0.125f
#define LOG2E 1.4426950408889634f
#define PSTR 40                 // plds row stride in bf16 (80 B)
#define VPAD 18                 // vbuf row stride in bf16 (36 B)
#define NTSTR (32*VPAD + 8)     // nt-subtile stride: 1168 B == 4 mod 32 dwords

typedef __attribute__((ext_vector_type(4))) float f32x4;
typedef __attribute__((ext_vector_type(4))) int   i32x4;
typedef __attribute__((ext_vector_type(8))) __bf16 bf16x8;

static __device__ __forceinline__ unsigned bfbits(float x) {
    union { __bf16 b; unsigned short u; } cv; cv.b = (__bf16)x; return (unsigned)cv.u;
}
static __device__ __forceinline__ bf16x8 cvt8(f32x4 a, f32x4 b) {
    bf16x8 f;
    f[0]=(__bf16)a[0]; f[1]=(__bf16)a[1]; f[2]=(__bf16)a[2]; f[3]=(__bf16)a[3];
    f[4]=(__bf16)b[0]; f[5]=(__bf16)b[1]; f[6]=(__bf16)b[2]; f[7]=(__bf16)b[3];
    return f;
}

struct WaveBuf {
    union {
        __bf16 vbuf[4 * NTSTR];      // V chunk, [nt][k][c] padded
        float  ctx[QBLK * DIM];      // ctx partial (used after PV)
    };
};
struct SharedT {
    WaveBuf sw[NWAVE];
    __bf16 plds[NWAVE][QBLK][PSTR];
    float red_m[QBLK][NWAVE];
    float red_s[QBLK][NWAVE];
};

__global__ __launch_bounds__(THREADS, 4)
void sdpa_mfma10(const float* __restrict__ Q, const float* __restrict__ K,
                 const float* __restrict__ V, const int* __restrict__ mask,
                 float* __restrict__ ctx_out, float* __restrict__ prob_out) {
    __shared__ SharedT su;

    // XCD-aware swizzle: 8192 = 8 XCDs x 1024 contiguous q-blocks (8 bh per XCD).
    const int rb   = ((blockIdx.x & 7) << 10) + (blockIdx.x >> 3);
    const int bh   = rb >> 7;
    const int q0   = (rb & 127) * QBLK;
    const int t    = threadIdx.x;
    const int lane = t & 63;
    const int w    = t >> 6;
    const int g    = lane >> 4;          // 0..3
    const int c    = lane & 15;          // lane's q-row (and N-col)

    const size_t bh_off = (size_t)bh * SEQ * DIM;
    const float* Qb = Q + bh_off;
    const float* Kb = K + bh_off;
    const float* Vb = V + bh_off;
    const int*   Mb = mask + (size_t)bh * SEQ * SEQ;
    const int wbase = w * KPW;

    // ---- Q^T B-fragments, kept in regs ----
    bf16x8 qf[2];
    {
        const float* qr = Qb + (size_t)(q0 + c) * DIM + 8 * g;
        qf[0] = cvt8(*(const f32x4*)(qr),      *(const f32x4*)(qr + 4));
        qf[1] = cvt8(*(const f32x4*)(qr + 32), *(const f32x4*)(qr + 36));
    }

    // =============== PASS 1: QK^T + online max/sum; mask -> bits ===============
    float m_run = -1e30f, s_run = 0.f;
    unsigned mbits0 = 0u, mbits1 = 0u;
    f32x4 kraw[2][4];
    i32x4 mraw[2];
    {   // prologue tile 0
        const float* kr = Kb + (size_t)(wbase + c) * DIM + 8 * g;
        kraw[0][0] = *(const f32x4*)(kr);
        kraw[0][1] = *(const f32x4*)(kr + 4);
        kraw[0][2] = *(const f32x4*)(kr + 32);
        kraw[0][3] = *(const f32x4*)(kr + 36);
        mraw[0] = *(const i32x4*)(Mb + (size_t)(q0 + c) * SEQ + wbase + 4 * g);
    }
    #pragma unroll
    for (int ct = 0; ct < NCT; ++ct) {
        const int cur = ct & 1, nxt = cur ^ 1;
        if (ct + 1 < NCT) {
            const float* kr = Kb + (size_t)(wbase + (ct + 1) * 16 + c) * DIM + 8 * g;
            kraw[nxt][0] = *(const f32x4*)(kr);
            kraw[nxt][1] = *(const f32x4*)(kr + 4);
            kraw[nxt][2] = *(const f32x4*)(kr + 32);
            kraw[nxt][3] = *(const f32x4*)(kr + 36);
            mraw[nxt] = *(const i32x4*)(Mb + (size_t)(q0 + c) * SEQ + wbase + (ct + 1) * 16 + 4 * g);
        }
        bf16x8 kf0 = cvt8(kraw[cur][0], kraw[cur][1]);
        bf16x8 kf1 = cvt8(kraw[cur][2], kraw[cur][3]);
        f32x4 acc = {0.f, 0.f, 0.f, 0.f};
        acc = __builtin_amdgcn_mfma_f32_16x16x32_bf16(kf0, qf[0], acc, 0, 0, 0);
        acc = __builtin_amdgcn_mfma_f32_16x16x32_bf16(kf1, qf[1], acc, 0, 0, 0);
        i32x4 mm = mraw[cur];
        float x0 = mm[0] ? -1e9f : acc[0] * SCALE;
        float x1 = mm[1] ? -1e9f : acc[1] * SCALE;
        float x2 = mm[2] ? -1e9f : acc[2] * SCALE;
        float x3 = mm[3] ? -1e9f : acc[3] * SCALE;
        unsigned bp = (mm[0]?1u:0u) | (mm[1]?2u:0u) | (mm[2]?4u:0u) | (mm[3]?8u:0u);
        if (ct < 8) mbits0 |= bp << (4 * ct); else mbits1 |= bp << (4 * (ct - 8));
        float tmax = fmaxf(fmaxf(x0, x1), fmaxf(x2, x3));
        float mnew = fmaxf(m_run, tmax);
        float rs = exp2f((m_run - mnew) * LOG2E);
        float e0 = exp2f((x0 - mnew) * LOG2E);
        float e1 = exp2f((x1 - mnew) * LOG2E);
        float e2 = exp2f((x2 - mnew) * LOG2E);
        float e3 = exp2f((x3 - mnew) * LOG2E);
        s_run = s_run * rs + ((e0 + e1) + (e2 + e3));
        m_run = mnew;
    }

    // ---- pass-2 prefetch issued before the reduction barriers ----
    const int r_st = lane >> 4;
    const int cw   = (4 * c) & 15;
    const int ntw  = c >> 2;
    f32x4 vrawA[4], vrawB[4], krA[4], krB[4];
    {
        const float* vsrc = Vb + (size_t)(wbase + r_st) * DIM + 4 * c;
        #pragma unroll
        for (int i = 0; i < 4; ++i) {
            vrawA[i] = *(const f32x4*)(vsrc + (size_t)(4 * i) * DIM);
            vrawB[i] = *(const f32x4*)(vsrc + (size_t)(16 + 4 * i) * DIM);
        }
        const float* ka = Kb + (size_t)(wbase + c) * DIM + 8 * g;        // tile 0
        krA[0] = *(const f32x4*)(ka);      krA[1] = *(const f32x4*)(ka + 4);
        krA[2] = *(const f32x4*)(ka + 32); krA[3] = *(const f32x4*)(ka + 36);
        const float* kb = Kb + (size_t)(wbase + 16 + c) * DIM + 8 * g;   // tile 1
        krB[0] = *(const f32x4*)(kb);      krB[1] = *(const f32x4*)(kb + 4);
        krB[2] = *(const f32x4*)(kb + 32); krB[3] = *(const f32x4*)(kb + 36);
    }

    // =============== M, S reductions (2 barriers) ===============
    float mw = fmaxf(m_run, __shfl_xor(m_run, 16));
    mw = fmaxf(mw, __shfl_xor(mw, 32));
    if (g == 0) su.red_m[c][w] = mw;
    __syncthreads();
    float M = su.red_m[c][0];
    #pragma unroll
    for (int i = 1; i < NWAVE; ++i) M = fmaxf(M, su.red_m[c][i]);

    float sadj = s_run * exp2f((m_run - M) * LOG2E);
    sadj += __shfl_xor(sadj, 16);
    sadj += __shfl_xor(sadj, 32);
    if (g == 0) su.red_s[c][w] = sadj;
    __syncthreads();
    float S = 0.f;
    #pragma unroll
    for (int i = 0; i < NWAVE; ++i) S += su.red_s[c][i];
    const float inv = 1.0f / S;

    // =============== PASS 2: recompute scores, prob, PV ===============
    f32x4 cacc[4];
    #pragma unroll
    for (int nt = 0; nt < 4; ++nt) cacc[nt] = (f32x4){0.f, 0.f, 0.f, 0.f};

    float* prow = prob_out + ((size_t)bh * SEQ + (q0 + c)) * SEQ + wbase;
    __bf16* vbufW = su.sw[w].vbuf;

    #pragma unroll
    for (int cc = 0; cc < NCHUNK; ++cc) {
        // stage V chunk (loaded last iteration / prologue)
        #pragma unroll
        for (int i = 0; i < 4; ++i) {
            ushort2 lo_, hi_;
            lo_.x = (unsigned short)bfbits(vrawA[i][0]);
            lo_.y = (unsigned short)bfbits(vrawA[i][1]);
            hi_.x = (unsigned short)bfbits(vrawA[i][2]);
            hi_.y = (unsigned short)bfbits(vrawA[i][3]);
            __bf16* p = &vbufW[ntw * NTSTR + (4 * i + r_st) * VPAD + cw];
            *(ushort2*)p = lo_;
            *(ushort2*)(p + 2) = hi_;
        }
        #pragma unroll
        for (int i = 0; i < 4; ++i) {
            ushort2 lo_, hi_;
            lo_.x = (unsigned short)bfbits(vrawB[i][0]);
            lo_.y = (unsigned short)bfbits(vrawB[i][1]);
            hi_.x = (unsigned short)bfbits(vrawB[i][2]);
            hi_.y = (unsigned short)bfbits(vrawB[i][3]);
            __bf16* p = &vbufW[ntw * NTSTR + (16 + 4 * i + r_st) * VPAD + cw];
            *(ushort2*)p = lo_;
            *(ushort2*)(p + 2) = hi_;
        }
        // issue next chunk's V loads
        if (cc + 1 < NCHUNK) {
            const float* vsrc = Vb + (size_t)(wbase + (cc + 1) * 32 + r_st) * DIM + 4 * c;
            #pragma unroll
            for (int i = 0; i < 4; ++i) {
                vrawA[i] = *(const f32x4*)(vsrc + (size_t)(4 * i) * DIM);
                vrawB[i] = *(const f32x4*)(vsrc + (size_t)(16 + 4 * i) * DIM);
            }
        }

        // tile A = 2cc : recompute scores (identical MFMA -> identical bits)
        f32x4 eA, eB;
        {
            bf16x8 kf0 = cvt8(krA[0], krA[1]);
            bf16x8 kf1 = cvt8(krA[2], krA[3]);
            f32x4 acc = {0.f, 0.f, 0.f, 0.f};
            acc = __builtin_amdgcn_mfma_f32_16x16x32_bf16(kf0, qf[0], acc, 0, 0, 0);
            acc = __builtin_amdgcn_mfma_f32_16x16x32_bf16(kf1, qf[1], acc, 0, 0, 0);
            if (cc + 1 < NCHUNK) {   // prefetch K tile 2(cc+1)
                const float* ka = Kb + (size_t)(wbase + (2 * cc + 2) * 16 + c) * DIM + 8 * g;
                krA[0] = *(const f32x4*)(ka);      krA[1] = *(const f32x4*)(ka + 4);
                krA[2] = *(const f32x4*)(ka + 32); krA[3] = *(const f32x4*)(ka + 36);
            }
            unsigned bq = ((cc < 4) ? (mbits0 >> (8 * cc)) : (mbits1 >> (8 * (cc - 4)))) & 0xFu;
            float x0 = (bq & 1u) ? -1e9f : acc[0] * SCALE;
            float x1 = (bq & 2u) ? -1e9f : acc[1] * SCALE;
            float x2 = (bq & 4u) ? -1e9f : acc[2] * SCALE;
            float x3 = (bq & 8u) ? -1e9f : acc[3] * SCALE;
            eA[0] = exp2f((x0 - M) * LOG2E);
            eA[1] = exp2f((x1 - M) * LOG2E);
            eA[2] = exp2f((x2 - M) * LOG2E);
            eA[3] = exp2f((x3 - M) * LOG2E);
        }
        // tile B = 2cc+1
        {
            bf16x8 kf0 = cvt8(krB[0], krB[1]);
            bf16x8 kf1 = cvt8(krB[2], krB[3]);
            f32x4 acc = {0.f, 0.f, 0.f, 0.f};
            acc = __builtin_amdgcn_mfma_f32_16x16x32_bf16(kf0, qf[0], acc, 0, 0, 0);
            acc = __builtin_amdgcn_mfma_f32_16x16x32_bf16(kf1, qf[1], acc, 0, 0, 0);
            if (cc + 1 < NCHUNK) {   // prefetch K tile 2(cc+1)+1
                const float* kb = Kb + (size_t)(wbase + (2 * cc + 3) * 16 + c) * DIM + 8 * g;
                krB[0] = *(const f32x4*)(kb);      krB[1] = *(const f32x4*)(kb + 4);
                krB[2] = *(const f32x4*)(kb + 32); krB[3] = *(const f32x4*)(kb + 36);
            }
            unsigned bq = ((cc < 4) ? (mbits0 >> (8 * cc + 4)) : (mbits1 >> (8 * (cc - 4) + 4))) & 0xFu;
            float x0 = (bq & 1u) ? -1e9f : acc[0] * SCALE;
            float x1 = (bq & 2u) ? -1e9f : acc[1] * SCALE;
            float x2 = (bq & 4u) ? -1e9f : acc[2] * SCALE;
            float x3 = (bq & 8u) ? -1e9f : acc[3] * SCALE;
            eB[0] = exp2f((x0 - M) * LOG2E);
            eB[1] = exp2f((x1 - M) * LOG2E);
            eB[2] = exp2f((x2 - M) * LOG2E);
            eB[3] = exp2f((x3 - M) * LOG2E);
        }

        // prob writes (normalized f32; the two 64B halves write-combine to full lines in L2)
        {
            f32x4 pnA = { eA[0] * inv, eA[1] * inv, eA[2] * inv, eA[3] * inv };
            f32x4 pnB = { eB[0] * inv, eB[1] * inv, eB[2] * inv, eB[3] * inv };
            *(f32x4*)(prow + 32 * cc + 4 * g)      = pnA;
            *(f32x4*)(prow + 32 * cc + 16 + 4 * g) = pnB;
        }

        // P (raw e, bf16) -> plds -> b128 A-frag
        {
            uint2 ua, ub;
            ua.x = bfbits(eA[0]) | (bfbits(eA[1]) << 16);
            ua.y = bfbits(eA[2]) | (bfbits(eA[3]) << 16);
            ub.x = bfbits(eB[0]) | (bfbits(eB[1]) << 16);
            ub.y = bfbits(eB[2]) | (bfbits(eB[3]) << 16);
            *(uint2*)&su.plds[w][c][4 * g]      = ua;
            *(uint2*)&su.plds[w][c][16 + 4 * g] = ub;
        }
        bf16x8 pf = *(const bf16x8*)&su.plds[w][c][8 * g];

        // V B-frags: conflict-free scalar column reads
        bf16x8 vfr[4];
        #pragma unroll
        for (int nt = 0; nt < 4; ++nt) {
            bf16x8 f;
            #pragma unroll
            for (int j = 0; j < 8; ++j)
                f[j] = vbufW[nt * NTSTR + (8 * g + j) * VPAD + c];
            vfr[nt] = f;
        }

        __builtin_amdgcn_s_setprio(1);
        #pragma unroll
        for (int nt = 0; nt < 4; ++nt)
            cacc[nt] = __builtin_amdgcn_mfma_f32_16x16x32_bf16(pf, vfr[nt], cacc[nt], 0, 0, 0);
        __builtin_amdgcn_s_setprio(0);
    }

    // =============== ctx partials (scaled by per-row inv) + cross-wave reduce ===============
    float invr[4];
    #pragma unroll
    for (int jr = 0; jr < 4; ++jr) invr[jr] = __shfl(inv, 4 * g + jr);
    #pragma unroll
    for (int nt = 0; nt < 4; ++nt)
        #pragma unroll
        for (int jr = 0; jr < 4; ++jr)
            su.sw[w].ctx[(4 * g + jr) * DIM + nt * 16 + c] = cacc[nt][jr] * invr[jr];
    __syncthreads();
    {
        int e = t * 2;
        float2 a = make_float2(0.f, 0.f);
        #pragma unroll
        for (int i = 0; i < NWAVE; ++i) {
            float2 v = *(const float2*)&su.sw[i].ctx[e];
            a.x += v.x; a.y += v.y;
        }
        *(float2*)(ctx_out + ((size_t)bh * SEQ + q0) * DIM + e) = a;
    }
}

extern "C" void kernel_launch(void* const* d_in, const int* in_sizes, int n_in,
                              void* d_out, int out_size, void* d_ws, size_t ws_size,
                              hipStream_t stream) {
    const float* Q = (const float*)d_in[0];
    const float* K = (const float*)d_in[1];
    const float* V = (const float*)d_in[2];
    const int* mask = (const int*)d_in[3];
    float* ctx  = (float*)d_out;
    float* prob = (float*)d_out + (size_t)4 * 16 * SEQ * DIM;

    dim3 grid(64 * (SEQ / QBLK));   // 8192, divisible by 8 XCDs
    dim3 block(THREADS);
    sdpa_mfma10<<<grid, block, 0, stream>>>(Q, K, V, mask, ctx, prob);
}

// Round 13
// 1032.419 us; speedup vs baseline: 2.2157x; 2.2157x over previous
//
#include <hip/hip_runtime.h>
#include <stdint.h>

// B=4,H=16,S=2048,D=64 fp32 SDPA with materialized attn_prob.
// r13: single QK^T pass, scores packed bf16 (32 regs); state diet (single K and
// V buffers) so 2 blocks/CU fit WITHOUT spills under launch_bounds(512,4).
#define SEQ 2048
#define DIM 64
#define QBLK 16
#define NWAVE 8
#define KPW 256
#define NCT 16
#define NCHUNK 8
#define THREADS 512
#define SCALE 0.125f
#define LOG2E 1.4426950408889634f
#define PSTR 40                 // plds row stride in bf16 (80 B)
#define VPAD 18                 // vbuf row stride in bf16 (36 B)
#define NTSTR (32*VPAD + 8)     // nt-subtile stride: 1168 B

typedef __attribute__((ext_vector_type(4))) float f32x4;
typedef __attribute__((ext_vector_type(4))) int   i32x4;
typedef __attribute__((ext_vector_type(8))) __bf16 bf16x8;

static __device__ __forceinline__ unsigned bfbits(float x) {
    union { __bf16 b; unsigned short u; } cv; cv.b = (__bf16)x; return (unsigned)cv.u;
}
static __device__ __forceinline__ float lo16(unsigned u) { return __uint_as_float(u << 16); }
static __device__ __forceinline__ float hi16(unsigned u) { return __uint_as_float(u & 0xffff0000u); }
static __device__ __forceinline__ bf16x8 cvt8(f32x4 a, f32x4 b) {
    bf16x8 f;
    f[0]=(__bf16)a[0]; f[1]=(__bf16)a[1]; f[2]=(__bf16)a[2]; f[3]=(__bf16)a[3];
    f[4]=(__bf16)b[0]; f[5]=(__bf16)b[1]; f[6]=(__bf16)b[2]; f[7]=(__bf16)b[3];
    return f;
}

struct WaveBuf {
    union {
        __bf16 vbuf[4 * NTSTR];      // V chunk, [nt][k][c] padded
        float  ctx[QBLK * DIM];      // ctx partial (used after PV)
    };
};
struct SharedT {
    WaveBuf sw[NWAVE];
    __bf16 plds[NWAVE][QBLK][PSTR];
    float red_m[QBLK][NWAVE];
    float red_s[QBLK][NWAVE];
};

__global__ __launch_bounds__(THREADS, 4)
void sdpa_mfma11(const float* __restrict__ Q, const float* __restrict__ K,
                 const float* __restrict__ V, const int* __restrict__ mask,
                 float* __restrict__ ctx_out, float* __restrict__ prob_out) {
    __shared__ SharedT su;

    // XCD-aware swizzle: 8192 = 8 XCDs x 1024 contiguous q-blocks (8 bh per XCD).
    const int rb   = ((blockIdx.x & 7) << 10) + (blockIdx.x >> 3);
    const int bh   = rb >> 7;
    const int q0   = (rb & 127) * QBLK;
    const int t    = threadIdx.x;
    const int lane = t & 63;
    const int w    = t >> 6;
    const int g    = lane >> 4;          // 0..3
    const int c    = lane & 15;          // lane's q-row (and N-col)

    const size_t bh_off = (size_t)bh * SEQ * DIM;
    const float* Qb = Q + bh_off;
    const float* Kb = K + bh_off;
    const float* Vb = V + bh_off;
    const int*   Mb = mask + (size_t)bh * SEQ * SEQ;
    const int wbase = w * KPW;

    // ---- Q^T B-fragments (dead after pass 1; regs recycle) ----
    bf16x8 qf[2];
    {
        const float* qr = Qb + (size_t)(q0 + c) * DIM + 8 * g;
        qf[0] = cvt8(*(const f32x4*)(qr),      *(const f32x4*)(qr + 4));
        qf[1] = cvt8(*(const f32x4*)(qr + 32), *(const f32x4*)(qr + 36));
    }

    // =============== QK^T: single K buffer, 2-deep mask, scores -> packed bf16 ===============
    unsigned sc_pk[2 * NCT];             // 64 scores as 32 packed bf16 pairs
    f32x4 kr[4];
    i32x4 mraw[2];
    {
        const float* k0 = Kb + (size_t)(wbase + c) * DIM + 8 * g;
        kr[0] = *(const f32x4*)(k0);      kr[1] = *(const f32x4*)(k0 + 4);
        kr[2] = *(const f32x4*)(k0 + 32); kr[3] = *(const f32x4*)(k0 + 36);
        mraw[0] = *(const i32x4*)(Mb + (size_t)(q0 + c) * SEQ + wbase + 4 * g);
    }
    #pragma unroll
    for (int ct = 0; ct < NCT; ++ct) {
        if (ct + 1 < NCT)   // mask prefetch (HBM stream) first
            mraw[(ct + 1) & 1] = *(const i32x4*)(Mb + (size_t)(q0 + c) * SEQ + wbase + (ct + 1) * 16 + 4 * g);
        bf16x8 kf0 = cvt8(kr[0], kr[1]);
        bf16x8 kf1 = cvt8(kr[2], kr[3]);
        if (ct + 1 < NCT) {  // K buffer free after cvt; reload for next tile (L2-hot)
            const float* kn = Kb + (size_t)(wbase + (ct + 1) * 16 + c) * DIM + 8 * g;
            kr[0] = *(const f32x4*)(kn);      kr[1] = *(const f32x4*)(kn + 4);
            kr[2] = *(const f32x4*)(kn + 32); kr[3] = *(const f32x4*)(kn + 36);
        }
        f32x4 acc = {0.f, 0.f, 0.f, 0.f};
        acc = __builtin_amdgcn_mfma_f32_16x16x32_bf16(kf0, qf[0], acc, 0, 0, 0);
        acc = __builtin_amdgcn_mfma_f32_16x16x32_bf16(kf1, qf[1], acc, 0, 0, 0);
        i32x4 mm = mraw[ct & 1];
        float x0 = mm[0] ? -1e9f : acc[0] * SCALE;
        float x1 = mm[1] ? -1e9f : acc[1] * SCALE;
        float x2 = mm[2] ? -1e9f : acc[2] * SCALE;
        float x3 = mm[3] ? -1e9f : acc[3] * SCALE;
        sc_pk[2 * ct]     = bfbits(x0) | (bfbits(x1) << 16);
        sc_pk[2 * ct + 1] = bfbits(x2) | (bfbits(x3) << 16);
    }

    // =============== softmax over packed scores (lane owns row q=c) ===============
    float mx = -3e38f;
    #pragma unroll
    for (int i = 0; i < 2 * NCT; ++i)
        mx = fmaxf(mx, fmaxf(lo16(sc_pk[i]), hi16(sc_pk[i])));
    mx = fmaxf(mx, __shfl_xor(mx, 16));
    mx = fmaxf(mx, __shfl_xor(mx, 32));
    if (g == 0) su.red_m[c][w] = mx;
    __syncthreads();
    float M = su.red_m[c][0];
    #pragma unroll
    for (int i = 1; i < NWAVE; ++i) M = fmaxf(M, su.red_m[c][i]);

    float sum = 0.f;
    #pragma unroll
    for (int i = 0; i < 2 * NCT; ++i) {
        float e0 = exp2f((lo16(sc_pk[i]) - M) * LOG2E);
        float e1 = exp2f((hi16(sc_pk[i]) - M) * LOG2E);
        sum += e0 + e1;
        sc_pk[i] = bfbits(e0) | (bfbits(e1) << 16);   // raw e, bf16-packed
    }
    sum += __shfl_xor(sum, 16);
    sum += __shfl_xor(sum, 32);
    if (g == 0) su.red_s[c][w] = sum;
    __syncthreads();
    float S = 0.f;
    #pragma unroll
    for (int i = 0; i < NWAVE; ++i) S += su.red_s[c][i];
    const float inv = 1.0f / S;
    float invr[4];
    #pragma unroll
    for (int jr = 0; jr < 4; ++jr) invr[jr] = __shfl(inv, 4 * g + jr);

    // =============== PV + prob write, single V buffer (half-chunk staging) ===============
    f32x4 cacc[4];
    #pragma unroll
    for (int nt = 0; nt < 4; ++nt) cacc[nt] = (f32x4){0.f, 0.f, 0.f, 0.f};

    const int r_st = lane >> 4;
    const int cw   = (4 * c) & 15;
    const int ntw  = c >> 2;
    float* prow = prob_out + ((size_t)bh * SEQ + (q0 + c)) * SEQ + wbase;
    __bf16* vbufW = su.sw[w].vbuf;

    #pragma unroll
    for (int cc = 0; cc < NCHUNK; ++cc) {
        const float* vsrc = Vb + (size_t)(wbase + cc * 32 + r_st) * DIM + 4 * c;
        f32x4 vraw[4];
        // half A: rows 0..15 of chunk
        #pragma unroll
        for (int i = 0; i < 4; ++i)
            vraw[i] = *(const f32x4*)(vsrc + (size_t)(4 * i) * DIM);
        #pragma unroll
        for (int i = 0; i < 4; ++i) {
            ushort2 lo_, hi_;
            lo_.x = (unsigned short)bfbits(vraw[i][0]);
            lo_.y = (unsigned short)bfbits(vraw[i][1]);
            hi_.x = (unsigned short)bfbits(vraw[i][2]);
            hi_.y = (unsigned short)bfbits(vraw[i][3]);
            __bf16* p = &vbufW[ntw * NTSTR + (4 * i + r_st) * VPAD + cw];
            *(ushort2*)p = lo_;
            *(ushort2*)(p + 2) = hi_;
        }
        // half B: rows 16..31 (reuse vraw)
        #pragma unroll
        for (int i = 0; i < 4; ++i)
            vraw[i] = *(const f32x4*)(vsrc + (size_t)(16 + 4 * i) * DIM);
        #pragma unroll
        for (int i = 0; i < 4; ++i) {
            ushort2 lo_, hi_;
            lo_.x = (unsigned short)bfbits(vraw[i][0]);
            lo_.y = (unsigned short)bfbits(vraw[i][1]);
            hi_.x = (unsigned short)bfbits(vraw[i][2]);
            hi_.y = (unsigned short)bfbits(vraw[i][3]);
            __bf16* p = &vbufW[ntw * NTSTR + (16 + 4 * i + r_st) * VPAD + cw];
            *(ushort2*)p = lo_;
            *(ushort2*)(p + 2) = hi_;
        }

        // prob writes (normalized f32) + plds (raw bf16 e)
        unsigned pkA0 = sc_pk[4 * cc],     pkA1 = sc_pk[4 * cc + 1];
        unsigned pkB0 = sc_pk[4 * cc + 2], pkB1 = sc_pk[4 * cc + 3];
        {
            f32x4 pnA = { lo16(pkA0) * inv, hi16(pkA0) * inv, lo16(pkA1) * inv, hi16(pkA1) * inv };
            f32x4 pnB = { lo16(pkB0) * inv, hi16(pkB0) * inv, lo16(pkB1) * inv, hi16(pkB1) * inv };
            *(f32x4*)(prow + 32 * cc + 4 * g)      = pnA;
            *(f32x4*)(prow + 32 * cc + 16 + 4 * g) = pnB;
        }
        {
            uint2 ua; ua.x = pkA0; ua.y = pkA1;
            uint2 ub; ub.x = pkB0; ub.y = pkB1;
            *(uint2*)&su.plds[w][c][4 * g]      = ua;
            *(uint2*)&su.plds[w][c][16 + 4 * g] = ub;
        }
        bf16x8 pf = *(const bf16x8*)&su.plds[w][c][8 * g];

        // V B-frags: conflict-free scalar column reads
        bf16x8 vfr[4];
        #pragma unroll
        for (int nt = 0; nt < 4; ++nt) {
            bf16x8 f;
            #pragma unroll
            for (int j = 0; j < 8; ++j)
                f[j] = vbufW[nt * NTSTR + (8 * g + j) * VPAD + c];
            vfr[nt] = f;
        }

        __builtin_amdgcn_s_setprio(1);
        #pragma unroll
        for (int nt = 0; nt < 4; ++nt)
            cacc[nt] = __builtin_amdgcn_mfma_f32_16x16x32_bf16(pf, vfr[nt], cacc[nt], 0, 0, 0);
        __builtin_amdgcn_s_setprio(0);
    }

    // =============== ctx partials (scaled by per-row inv) + cross-wave reduce ===============
    #pragma unroll
    for (int nt = 0; nt < 4; ++nt)
        #pragma unroll
        for (int jr = 0; jr < 4; ++jr)
            su.sw[w].ctx[(4 * g + jr) * DIM + nt * 16 + c] = cacc[nt][jr] * invr[jr];
    __syncthreads();
    {
        int e = t * 2;
        float2 a = make_float2(0.f, 0.f);
        #pragma unroll
        for (int i = 0; i < NWAVE; ++i) {
            float2 v = *(const float2*)&su.sw[i].ctx[e];
            a.x += v.x; a.y += v.y;
        }
        *(float2*)(ctx_out + ((size_t)bh * SEQ + q0) * DIM + e) = a;
    }
}

extern "C" void kernel_launch(void* const* d_in, const int* in_sizes, int n_in,
                              void* d_out, int out_size, void* d_ws, size_t ws_size,
                              hipStream_t stream) {
    const float* Q = (const float*)d_in[0];
    const float* K = (const float*)d_in[1];
    const float* V = (const float*)d_in[2];
    const int* mask = (const int*)d_in[3];
    float* ctx  = (float*)d_out;
    float* prob = (float*)d_out + (size_t)4 * 16 * SEQ * DIM;

    dim3 grid(64 * (SEQ / QBLK));   // 8192, divisible by 8 XCDs
    dim3 block(THREADS);
    sdpa_mfma11<<<grid, block, 0, stream>>>(Q, K, V, mask, ctx, prob);
}

// Round 14
// 1010.305 us; speedup vs baseline: 2.2642x; 1.0219x over previous
//
#include <hip/hip_runtime.h>
#include <stdint.h>

// B=4,H=16,S=2048,D=64 fp32 SDPA with materialized attn_prob.
// r14: decoupled batched mask stream (bits in 2 VGPRs, QK^T never waits on mask),
// V chunk prefetch restored (r8 pattern), spill-free at 2 blocks/CU.
#define SEQ 2048
#define DIM 64
#define QBLK 16
#define NWAVE 8
#define KPW 256
#define NCT 16
#define NCHUNK 8
#define THREADS 512
#define SCALE 0.125f
#define LOG2E 1.4426950408889634f
#define PSTR 40                 // plds row stride in bf16 (80 B)
#define VPAD 18                 // vbuf row stride in bf16 (36 B)
#define NTSTR (32*VPAD + 8)     // nt-subtile stride: 1168 B

typedef __attribute__((ext_vector_type(4))) float f32x4;
typedef __attribute__((ext_vector_type(4))) int   i32x4;
typedef __attribute__((ext_vector_type(8))) __bf16 bf16x8;

static __device__ __forceinline__ unsigned bfbits(float x) {
    union { __bf16 b; unsigned short u; } cv; cv.b = (__bf16)x; return (unsigned)cv.u;
}
static __device__ __forceinline__ float lo16(unsigned u) { return __uint_as_float(u << 16); }
static __device__ __forceinline__ float hi16(unsigned u) { return __uint_as_float(u & 0xffff0000u); }
static __device__ __forceinline__ bf16x8 cvt8(f32x4 a, f32x4 b) {
    bf16x8 f;
    f[0]=(__bf16)a[0]; f[1]=(__bf16)a[1]; f[2]=(__bf16)a[2]; f[3]=(__bf16)a[3];
    f[4]=(__bf16)b[0]; f[5]=(__bf16)b[1]; f[6]=(__bf16)b[2]; f[7]=(__bf16)b[3];
    return f;
}
static __device__ __forceinline__ unsigned nib4(i32x4 mm) {
    return (mm[0]?1u:0u) | (mm[1]?2u:0u) | (mm[2]?4u:0u) | (mm[3]?8u:0u);
}

struct WaveBuf {
    union {
        __bf16 vbuf[4 * NTSTR];      // V chunk, [nt][k][c] padded
        float  ctx[QBLK * DIM];      // ctx partial (used after PV)
    };
};
struct SharedT {
    WaveBuf sw[NWAVE];
    __bf16 plds[NWAVE][QBLK][PSTR];
    float red_m[QBLK][NWAVE];
    float red_s[QBLK][NWAVE];
};

__global__ __launch_bounds__(THREADS, 4)
void sdpa_mfma12(const float* __restrict__ Q, const float* __restrict__ K,
                 const float* __restrict__ V, const int* __restrict__ mask,
                 float* __restrict__ ctx_out, float* __restrict__ prob_out) {
    __shared__ SharedT su;

    // XCD-aware swizzle: 8192 = 8 XCDs x 1024 contiguous q-blocks (8 bh per XCD).
    const int rb   = ((blockIdx.x & 7) << 10) + (blockIdx.x >> 3);
    const int bh   = rb >> 7;
    const int q0   = (rb & 127) * QBLK;
    const int t    = threadIdx.x;
    const int lane = t & 63;
    const int w    = t >> 6;
    const int g    = lane >> 4;          // 0..3
    const int c    = lane & 15;          // lane's q-row (and N-col)

    const size_t bh_off = (size_t)bh * SEQ * DIM;
    const float* Qb = Q + bh_off;
    const float* Kb = K + bh_off;
    const float* Vb = V + bh_off;
    const int*   Mb = mask + (size_t)bh * SEQ * SEQ;
    const int wbase = w * KPW;

    // ---- Q^T B-fragments ----
    bf16x8 qf[2];
    {
        const float* qr = Qb + (size_t)(q0 + c) * DIM + 8 * g;
        qf[0] = cvt8(*(const f32x4*)(qr),      *(const f32x4*)(qr + 4));
        qf[1] = cvt8(*(const f32x4*)(qr + 32), *(const f32x4*)(qr + 36));
    }

    // =============== QK^T with DECOUPLED mask stream ===============
    // mask: 2 batches x 4 tiles in flight (8 KB/wave); converted to bits on arrival.
    unsigned sc_pk[2 * NCT];             // 64 scores, packed bf16, UNMASKED
    unsigned mbits0 = 0u, mbits1 = 0u;   // 64 mask bits (4 per tile)
    const int* mrow = Mb + (size_t)(q0 + c) * SEQ + wbase + 4 * g;
    i32x4 mq0[4], mq1[4];
    #pragma unroll
    for (int j = 0; j < 4; ++j) mq0[j] = *(const i32x4*)(mrow + 16 * j);          // tiles 0-3
    #pragma unroll
    for (int j = 0; j < 4; ++j) mq1[j] = *(const i32x4*)(mrow + 16 * (4 + j));    // tiles 4-7

    f32x4 kr[4];
    {
        const float* k0 = Kb + (size_t)(wbase + c) * DIM + 8 * g;
        kr[0] = *(const f32x4*)(k0);      kr[1] = *(const f32x4*)(k0 + 4);
        kr[2] = *(const f32x4*)(k0 + 32); kr[3] = *(const f32x4*)(k0 + 36);
    }

    #pragma unroll
    for (int ct = 0; ct < NCT; ++ct) {
        // batch rotation (compile-time branches; loop fully unrolled)
        if (ct == 4) {   // consume tiles 0-3, re-arm with tiles 8-11
            #pragma unroll
            for (int j = 0; j < 4; ++j) mbits0 |= nib4(mq0[j]) << (4 * j);
            #pragma unroll
            for (int j = 0; j < 4; ++j) mq0[j] = *(const i32x4*)(mrow + 16 * (8 + j));
        }
        if (ct == 8) {   // consume tiles 4-7, re-arm with tiles 12-15
            #pragma unroll
            for (int j = 0; j < 4; ++j) mbits0 |= nib4(mq1[j]) << (4 * (4 + j));
            #pragma unroll
            for (int j = 0; j < 4; ++j) mq1[j] = *(const i32x4*)(mrow + 16 * (12 + j));
        }
        if (ct == 12) {  // consume tiles 8-11
            #pragma unroll
            for (int j = 0; j < 4; ++j) mbits1 |= nib4(mq0[j]) << (4 * j);
        }

        bf16x8 kf0 = cvt8(kr[0], kr[1]);
        bf16x8 kf1 = cvt8(kr[2], kr[3]);
        if (ct + 1 < NCT) {  // K reload (L2-hot via XCD swizzle)
            const float* kn = Kb + (size_t)(wbase + (ct + 1) * 16 + c) * DIM + 8 * g;
            kr[0] = *(const f32x4*)(kn);      kr[1] = *(const f32x4*)(kn + 4);
            kr[2] = *(const f32x4*)(kn + 32); kr[3] = *(const f32x4*)(kn + 36);
        }
        f32x4 acc = {0.f, 0.f, 0.f, 0.f};
        acc = __builtin_amdgcn_mfma_f32_16x16x32_bf16(kf0, qf[0], acc, 0, 0, 0);
        acc = __builtin_amdgcn_mfma_f32_16x16x32_bf16(kf1, qf[1], acc, 0, 0, 0);
        sc_pk[2 * ct]     = bfbits(acc[0] * SCALE) | (bfbits(acc[1] * SCALE) << 16);
        sc_pk[2 * ct + 1] = bfbits(acc[2] * SCALE) | (bfbits(acc[3] * SCALE) << 16);
    }

    // ---- V chunk-0 prefetch: issue BEFORE mask finalize + softmax barriers ----
    const int r_st = lane >> 4;
    const int cw   = (4 * c) & 15;
    const int ntw  = c >> 2;
    f32x4 vrawA[4], vrawB[4];
    {
        const float* vsrc = Vb + (size_t)(wbase + r_st) * DIM + 4 * c;
        #pragma unroll
        for (int i = 0; i < 4; ++i) {
            vrawA[i] = *(const f32x4*)(vsrc + (size_t)(4 * i) * DIM);
            vrawB[i] = *(const f32x4*)(vsrc + (size_t)(16 + 4 * i) * DIM);
        }
    }

    // finalize mask bits (tiles 12-15; loads long in flight)
    #pragma unroll
    for (int j = 0; j < 4; ++j) mbits1 |= nib4(mq1[j]) << (4 * (4 + j));

    // apply mask to packed scores (branchless select)
    #pragma unroll
    for (int ct = 0; ct < NCT; ++ct) {
        unsigned nib = ((ct < 8) ? (mbits0 >> (4 * ct)) : (mbits1 >> (4 * (ct - 8)))) & 0xFu;
        float x0 = (nib & 1u) ? -1e9f : lo16(sc_pk[2 * ct]);
        float x1 = (nib & 2u) ? -1e9f : hi16(sc_pk[2 * ct]);
        float x2 = (nib & 4u) ? -1e9f : lo16(sc_pk[2 * ct + 1]);
        float x3 = (nib & 8u) ? -1e9f : hi16(sc_pk[2 * ct + 1]);
        sc_pk[2 * ct]     = bfbits(x0) | (bfbits(x1) << 16);
        sc_pk[2 * ct + 1] = bfbits(x2) | (bfbits(x3) << 16);
    }

    // =============== softmax (lane owns row q=c) ===============
    float mx = -3e38f;
    #pragma unroll
    for (int i = 0; i < 2 * NCT; ++i)
        mx = fmaxf(mx, fmaxf(lo16(sc_pk[i]), hi16(sc_pk[i])));
    mx = fmaxf(mx, __shfl_xor(mx, 16));
    mx = fmaxf(mx, __shfl_xor(mx, 32));
    if (g == 0) su.red_m[c][w] = mx;
    __syncthreads();
    float M = su.red_m[c][0];
    #pragma unroll
    for (int i = 1; i < NWAVE; ++i) M = fmaxf(M, su.red_m[c][i]);

    float sum = 0.f;
    #pragma unroll
    for (int i = 0; i < 2 * NCT; ++i) {
        float e0 = exp2f((lo16(sc_pk[i]) - M) * LOG2E);
        float e1 = exp2f((hi16(sc_pk[i]) - M) * LOG2E);
        sum += e0 + e1;
        sc_pk[i] = bfbits(e0) | (bfbits(e1) << 16);   // raw e, bf16-packed
    }
    sum += __shfl_xor(sum, 16);
    sum += __shfl_xor(sum, 32);
    if (g == 0) su.red_s[c][w] = sum;
    __syncthreads();
    float S = 0.f;
    #pragma unroll
    for (int i = 0; i < NWAVE; ++i) S += su.red_s[c][i];
    const float inv = 1.0f / S;
    float invr[4];
    #pragma unroll
    for (int jr = 0; jr < 4; ++jr) invr[jr] = __shfl(inv, 4 * g + jr);

    // =============== PV + prob write, stage-then-reload V pipeline (r8) ===============
    f32x4 cacc[4];
    #pragma unroll
    for (int nt = 0; nt < 4; ++nt) cacc[nt] = (f32x4){0.f, 0.f, 0.f, 0.f};

    float* prow = prob_out + ((size_t)bh * SEQ + (q0 + c)) * SEQ + wbase;
    __bf16* vbufW = su.sw[w].vbuf;

    #pragma unroll
    for (int cc = 0; cc < NCHUNK; ++cc) {
        // stage chunk loaded last iteration / prologue
        #pragma unroll
        for (int i = 0; i < 4; ++i) {
            ushort2 lo_, hi_;
            lo_.x = (unsigned short)bfbits(vrawA[i][0]);
            lo_.y = (unsigned short)bfbits(vrawA[i][1]);
            hi_.x = (unsigned short)bfbits(vrawA[i][2]);
            hi_.y = (unsigned short)bfbits(vrawA[i][3]);
            __bf16* p = &vbufW[ntw * NTSTR + (4 * i + r_st) * VPAD + cw];
            *(ushort2*)p = lo_;
            *(ushort2*)(p + 2) = hi_;
        }
        #pragma unroll
        for (int i = 0; i < 4; ++i) {
            ushort2 lo_, hi_;
            lo_.x = (unsigned short)bfbits(vrawB[i][0]);
            lo_.y = (unsigned short)bfbits(vrawB[i][1]);
            hi_.x = (unsigned short)bfbits(vrawB[i][2]);
            hi_.y = (unsigned short)bfbits(vrawB[i][3]);
            __bf16* p = &vbufW[ntw * NTSTR + (16 + 4 * i + r_st) * VPAD + cw];
            *(ushort2*)p = lo_;
            *(ushort2*)(p + 2) = hi_;
        }
        // issue NEXT chunk's loads (in flight under frag reads + MFMA)
        if (cc + 1 < NCHUNK) {
            const float* vsrc = Vb + (size_t)(wbase + (cc + 1) * 32 + r_st) * DIM + 4 * c;
            #pragma unroll
            for (int i = 0; i < 4; ++i) {
                vrawA[i] = *(const f32x4*)(vsrc + (size_t)(4 * i) * DIM);
                vrawB[i] = *(const f32x4*)(vsrc + (size_t)(16 + 4 * i) * DIM);
            }
        }

        // prob writes (normalized f32) + plds (raw bf16 e)
        unsigned pkA0 = sc_pk[4 * cc],     pkA1 = sc_pk[4 * cc + 1];
        unsigned pkB0 = sc_pk[4 * cc + 2], pkB1 = sc_pk[4 * cc + 3];
        {
            f32x4 pnA = { lo16(pkA0) * inv, hi16(pkA0) * inv, lo16(pkA1) * inv, hi16(pkA1) * inv };
            f32x4 pnB = { lo16(pkB0) * inv, hi16(pkB0) * inv, lo16(pkB1) * inv, hi16(pkB1) * inv };
            *(f32x4*)(prow + 32 * cc + 4 * g)      = pnA;
            *(f32x4*)(prow + 32 * cc + 16 + 4 * g) = pnB;
        }
        {
            uint2 ua; ua.x = pkA0; ua.y = pkA1;
            uint2 ub; ub.x = pkB0; ub.y = pkB1;
            *(uint2*)&su.plds[w][c][4 * g]      = ua;
            *(uint2*)&su.plds[w][c][16 + 4 * g] = ub;
        }
        bf16x8 pf = *(const bf16x8*)&su.plds[w][c][8 * g];

        // V B-frags: conflict-free scalar column reads
        bf16x8 vfr[4];
        #pragma unroll
        for (int nt = 0; nt < 4; ++nt) {
            bf16x8 f;
            #pragma unroll
            for (int j = 0; j < 8; ++j)
                f[j] = vbufW[nt * NTSTR + (8 * g + j) * VPAD + c];
            vfr[nt] = f;
        }

        __builtin_amdgcn_s_setprio(1);
        #pragma unroll
        for (int nt = 0; nt < 4; ++nt)
            cacc[nt] = __builtin_amdgcn_mfma_f32_16x16x32_bf16(pf, vfr[nt], cacc[nt], 0, 0, 0);
        __builtin_amdgcn_s_setprio(0);
    }

    // =============== ctx partials (scaled by per-row inv) + cross-wave reduce ===============
    #pragma unroll
    for (int nt = 0; nt < 4; ++nt)
        #pragma unroll
        for (int jr = 0; jr < 4; ++jr)
            su.sw[w].ctx[(4 * g + jr) * DIM + nt * 16 + c] = cacc[nt][jr] * invr[jr];
    __syncthreads();
    {
        int e = t * 2;
        float2 a = make_float2(0.f, 0.f);
        #pragma unroll
        for (int i = 0; i < NWAVE; ++i) {
            float2 v = *(const float2*)&su.sw[i].ctx[e];
            a.x += v.x; a.y += v.y;
        }
        *(float2*)(ctx_out + ((size_t)bh * SEQ + q0) * DIM + e) = a;
    }
}

extern "C" void kernel_launch(void* const* d_in, const int* in_sizes, int n_in,
                              void* d_out, int out_size, void* d_ws, size_t ws_size,
                              hipStream_t stream) {
    const float* Q = (const float*)d_in[0];
    const float* K = (const float*)d_in[1];
    const float* V = (const float*)d_in[2];
    const int* mask = (const int*)d_in[3];
    float* ctx  = (float*)d_out;
    float* prob = (float*)d_out + (size_t)4 * 16 * SEQ * DIM;

    dim3 grid(64 * (SEQ / QBLK));   // 8192, divisible by 8 XCDs
    dim3 block(THREADS);
    sdpa_mfma12<<<grid, block, 0, stream>>>(Q, K, V, mask, ctx, prob);
}

// Round 15
// 979.109 us; speedup vs baseline: 2.3363x; 1.0319x over previous
//
#include <hip/hip_runtime.h>
#include <stdint.h>

// B=4,H=16,S=2048,D=64 fp32 SDPA with materialized attn_prob.
// r15: QK^T as 2 half-passes with CLEAN VMEM queues — each half issues its full
// 8-tile mask batch (HBM stream) BEFORE its K loop (L2 stream), so in-order
// VMEM retirement costs exactly ONE mask-drain stall per half instead of
// leaking HBM latency into every K wait. PV pipeline unchanged (r14).
#define SEQ 2048
#define DIM 64
#define QBLK 16
#define NWAVE 8
#define KPW 256
#define NCT 16
#define NCHUNK 8
#define THREADS 512
#define SCALE 0.125f
#define LOG2E 1.4426950408889634f
#define PSTR 40                 // plds row stride in bf16 (80 B)
#define VPAD 18                 // vbuf row stride in bf16 (36 B)
#define NTSTR (32*VPAD + 8)     // nt-subtile stride: 1168 B

typedef __attribute__((ext_vector_type(4))) float f32x4;
typedef __attribute__((ext_vector_type(4))) int   i32x4;
typedef __attribute__((ext_vector_type(8))) __bf16 bf16x8;

static __device__ __forceinline__ unsigned bfbits(float x) {
    union { __bf16 b; unsigned short u; } cv; cv.b = (__bf16)x; return (unsigned)cv.u;
}
static __device__ __forceinline__ float lo16(unsigned u) { return __uint_as_float(u << 16); }
static __device__ __forceinline__ float hi16(unsigned u) { return __uint_as_float(u & 0xffff0000u); }
static __device__ __forceinline__ bf16x8 cvt8(f32x4 a, f32x4 b) {
    bf16x8 f;
    f[0]=(__bf16)a[0]; f[1]=(__bf16)a[1]; f[2]=(__bf16)a[2]; f[3]=(__bf16)a[3];
    f[4]=(__bf16)b[0]; f[5]=(__bf16)b[1]; f[6]=(__bf16)b[2]; f[7]=(__bf16)b[3];
    return f;
}
static __device__ __forceinline__ unsigned nib4(i32x4 mm) {
    return (mm[0]?1u:0u) | (mm[1]?2u:0u) | (mm[2]?4u:0u) | (mm[3]?8u:0u);
}

struct WaveBuf {
    union {
        __bf16 vbuf[4 * NTSTR];      // V chunk, [nt][k][c] padded
        float  ctx[QBLK * DIM];      // ctx partial (used after PV)
    };
};
struct SharedT {
    WaveBuf sw[NWAVE];
    __bf16 plds[NWAVE][QBLK][PSTR];
    float red_m[QBLK][NWAVE];
    float red_s[QBLK][NWAVE];
};

__global__ __launch_bounds__(THREADS, 4)
void sdpa_mfma13(const float* __restrict__ Q, const float* __restrict__ K,
                 const float* __restrict__ V, const int* __restrict__ mask,
                 float* __restrict__ ctx_out, float* __restrict__ prob_out) {
    __shared__ SharedT su;

    // XCD-aware swizzle: 8192 = 8 XCDs x 1024 contiguous q-blocks (8 bh per XCD).
    const int rb   = ((blockIdx.x & 7) << 10) + (blockIdx.x >> 3);
    const int bh   = rb >> 7;
    const int q0   = (rb & 127) * QBLK;
    const int t    = threadIdx.x;
    const int lane = t & 63;
    const int w    = t >> 6;
    const int g    = lane >> 4;          // 0..3
    const int c    = lane & 15;          // lane's q-row (and N-col)

    const size_t bh_off = (size_t)bh * SEQ * DIM;
    const float* Qb = Q + bh_off;
    const float* Kb = K + bh_off;
    const float* Vb = V + bh_off;
    const int*   Mb = mask + (size_t)bh * SEQ * SEQ;
    const int wbase = w * KPW;

    // ---- Q^T B-fragments ----
    bf16x8 qf[2];
    {
        const float* qr = Qb + (size_t)(q0 + c) * DIM + 8 * g;
        qf[0] = cvt8(*(const f32x4*)(qr),      *(const f32x4*)(qr + 4));
        qf[1] = cvt8(*(const f32x4*)(qr + 32), *(const f32x4*)(qr + 36));
    }

    // =============== QK^T in 2 half-passes with clean VMEM queues ===============
    unsigned sc_pk[2 * NCT];             // 64 scores, packed bf16, UNMASKED
    unsigned mbits0 = 0u, mbits1 = 0u;   // 64 mask bits (4 per tile)
    const int* mrow = Mb + (size_t)(q0 + c) * SEQ + wbase + 4 * g;
    f32x4 kr[4];
    i32x4 mq[8];

    // ---- half 1: mask tiles 0-7 issued FIRST, then K-only loop ----
    #pragma unroll
    for (int j = 0; j < 8; ++j) mq[j] = *(const i32x4*)(mrow + 16 * j);
    __builtin_amdgcn_sched_barrier(0);   // pin: mask batch issues before anything below
    {
        const float* k0 = Kb + (size_t)(wbase + c) * DIM + 8 * g;
        kr[0] = *(const f32x4*)(k0);      kr[1] = *(const f32x4*)(k0 + 4);
        kr[2] = *(const f32x4*)(k0 + 32); kr[3] = *(const f32x4*)(k0 + 36);
    }
    #pragma unroll
    for (int ct = 0; ct < 8; ++ct) {
        bf16x8 kf0 = cvt8(kr[0], kr[1]);   // first iter: one mask-batch drain; rest clean
        bf16x8 kf1 = cvt8(kr[2], kr[3]);
        {   // reload next tile's K (tile 8 at ct==7 feeds half 2 seamlessly)
            const float* kn = Kb + (size_t)(wbase + (ct + 1) * 16 + c) * DIM + 8 * g;
            kr[0] = *(const f32x4*)(kn);      kr[1] = *(const f32x4*)(kn + 4);
            kr[2] = *(const f32x4*)(kn + 32); kr[3] = *(const f32x4*)(kn + 36);
        }
        f32x4 acc = {0.f, 0.f, 0.f, 0.f};
        acc = __builtin_amdgcn_mfma_f32_16x16x32_bf16(kf0, qf[0], acc, 0, 0, 0);
        acc = __builtin_amdgcn_mfma_f32_16x16x32_bf16(kf1, qf[1], acc, 0, 0, 0);
        sc_pk[2 * ct]     = bfbits(acc[0] * SCALE) | (bfbits(acc[1] * SCALE) << 16);
        sc_pk[2 * ct + 1] = bfbits(acc[2] * SCALE) | (bfbits(acc[3] * SCALE) << 16);
    }
    #pragma unroll
    for (int j = 0; j < 8; ++j) mbits0 |= nib4(mq[j]) << (4 * j);   // loads long retired

    // ---- half 2: mask tiles 8-15 issued FIRST, then K-only loop ----
    #pragma unroll
    for (int j = 0; j < 8; ++j) mq[j] = *(const i32x4*)(mrow + 16 * (8 + j));
    __builtin_amdgcn_sched_barrier(0);
    #pragma unroll
    for (int ct = 8; ct < NCT; ++ct) {
        bf16x8 kf0 = cvt8(kr[0], kr[1]);   // ct=8's K was issued BEFORE the mask batch: clean
        bf16x8 kf1 = cvt8(kr[2], kr[3]);
        if (ct + 1 < NCT) {
            const float* kn = Kb + (size_t)(wbase + (ct + 1) * 16 + c) * DIM + 8 * g;
            kr[0] = *(const f32x4*)(kn);      kr[1] = *(const f32x4*)(kn + 4);
            kr[2] = *(const f32x4*)(kn + 32); kr[3] = *(const f32x4*)(kn + 36);
        }
        f32x4 acc = {0.f, 0.f, 0.f, 0.f};
        acc = __builtin_amdgcn_mfma_f32_16x16x32_bf16(kf0, qf[0], acc, 0, 0, 0);
        acc = __builtin_amdgcn_mfma_f32_16x16x32_bf16(kf1, qf[1], acc, 0, 0, 0);
        sc_pk[2 * ct]     = bfbits(acc[0] * SCALE) | (bfbits(acc[1] * SCALE) << 16);
        sc_pk[2 * ct + 1] = bfbits(acc[2] * SCALE) | (bfbits(acc[3] * SCALE) << 16);
    }
    #pragma unroll
    for (int j = 0; j < 8; ++j) mbits1 |= nib4(mq[j]) << (4 * j);

    // ---- V chunk-0 prefetch: in flight across mask sweep + softmax barriers ----
    const int r_st = lane >> 4;
    const int cw   = (4 * c) & 15;
    const int ntw  = c >> 2;
    f32x4 vrawA[4], vrawB[4];
    {
        const float* vsrc = Vb + (size_t)(wbase + r_st) * DIM + 4 * c;
        #pragma unroll
        for (int i = 0; i < 4; ++i) {
            vrawA[i] = *(const f32x4*)(vsrc + (size_t)(4 * i) * DIM);
            vrawB[i] = *(const f32x4*)(vsrc + (size_t)(16 + 4 * i) * DIM);
        }
    }

    // apply mask to packed scores (branchless select)
    #pragma unroll
    for (int ct = 0; ct < NCT; ++ct) {
        unsigned nib = ((ct < 8) ? (mbits0 >> (4 * ct)) : (mbits1 >> (4 * (ct - 8)))) & 0xFu;
        float x0 = (nib & 1u) ? -1e9f : lo16(sc_pk[2 * ct]);
        float x1 = (nib & 2u) ? -1e9f : hi16(sc_pk[2 * ct]);
        float x2 = (nib & 4u) ? -1e9f : lo16(sc_pk[2 * ct + 1]);
        float x3 = (nib & 8u) ? -1e9f : hi16(sc_pk[2 * ct + 1]);
        sc_pk[2 * ct]     = bfbits(x0) | (bfbits(x1) << 16);
        sc_pk[2 * ct + 1] = bfbits(x2) | (bfbits(x3) << 16);
    }

    // =============== softmax (lane owns row q=c) ===============
    float mx = -3e38f;
    #pragma unroll
    for (int i = 0; i < 2 * NCT; ++i)
        mx = fmaxf(mx, fmaxf(lo16(sc_pk[i]), hi16(sc_pk[i])));
    mx = fmaxf(mx, __shfl_xor(mx, 16));
    mx = fmaxf(mx, __shfl_xor(mx, 32));
    if (g == 0) su.red_m[c][w] = mx;
    __syncthreads();
    float M = su.red_m[c][0];
    #pragma unroll
    for (int i = 1; i < NWAVE; ++i) M = fmaxf(M, su.red_m[c][i]);

    float sum = 0.f;
    #pragma unroll
    for (int i = 0; i < 2 * NCT; ++i) {
        float e0 = exp2f((lo16(sc_pk[i]) - M) * LOG2E);
        float e1 = exp2f((hi16(sc_pk[i]) - M) * LOG2E);
        sum += e0 + e1;
        sc_pk[i] = bfbits(e0) | (bfbits(e1) << 16);   // raw e, bf16-packed
    }
    sum += __shfl_xor(sum, 16);
    sum += __shfl_xor(sum, 32);
    if (g == 0) su.red_s[c][w] = sum;
    __syncthreads();
    float S = 0.f;
    #pragma unroll
    for (int i = 0; i < NWAVE; ++i) S += su.red_s[c][i];
    const float inv = 1.0f / S;
    float invr[4];
    #pragma unroll
    for (int jr = 0; jr < 4; ++jr) invr[jr] = __shfl(inv, 4 * g + jr);

    // =============== PV + prob write, stage-then-reload V pipeline ===============
    f32x4 cacc[4];
    #pragma unroll
    for (int nt = 0; nt < 4; ++nt) cacc[nt] = (f32x4){0.f, 0.f, 0.f, 0.f};

    float* prow = prob_out + ((size_t)bh * SEQ + (q0 + c)) * SEQ + wbase;
    __bf16* vbufW = su.sw[w].vbuf;

    #pragma unroll
    for (int cc = 0; cc < NCHUNK; ++cc) {
        // stage chunk loaded last iteration / prologue
        #pragma unroll
        for (int i = 0; i < 4; ++i) {
            ushort2 lo_, hi_;
            lo_.x = (unsigned short)bfbits(vrawA[i][0]);
            lo_.y = (unsigned short)bfbits(vrawA[i][1]);
            hi_.x = (unsigned short)bfbits(vrawA[i][2]);
            hi_.y = (unsigned short)bfbits(vrawA[i][3]);
            __bf16* p = &vbufW[ntw * NTSTR + (4 * i + r_st) * VPAD + cw];
            *(ushort2*)p = lo_;
            *(ushort2*)(p + 2) = hi_;
        }
        #pragma unroll
        for (int i = 0; i < 4; ++i) {
            ushort2 lo_, hi_;
            lo_.x = (unsigned short)bfbits(vrawB[i][0]);
            lo_.y = (unsigned short)bfbits(vrawB[i][1]);
            hi_.x = (unsigned short)bfbits(vrawB[i][2]);
            hi_.y = (unsigned short)bfbits(vrawB[i][3]);
            __bf16* p = &vbufW[ntw * NTSTR + (16 + 4 * i + r_st) * VPAD + cw];
            *(ushort2*)p = lo_;
            *(ushort2*)(p + 2) = hi_;
        }
        // issue NEXT chunk's loads (only loads in this phase's queue)
        if (cc + 1 < NCHUNK) {
            const float* vsrc = Vb + (size_t)(wbase + (cc + 1) * 32 + r_st) * DIM + 4 * c;
            #pragma unroll
            for (int i = 0; i < 4; ++i) {
                vrawA[i] = *(const f32x4*)(vsrc + (size_t)(4 * i) * DIM);
                vrawB[i] = *(const f32x4*)(vsrc + (size_t)(16 + 4 * i) * DIM);
            }
        }

        // prob writes (normalized f32) + plds (raw bf16 e)
        unsigned pkA0 = sc_pk[4 * cc],     pkA1 = sc_pk[4 * cc + 1];
        unsigned pkB0 = sc_pk[4 * cc + 2], pkB1 = sc_pk[4 * cc + 3];
        {
            f32x4 pnA = { lo16(pkA0) * inv, hi16(pkA0) * inv, lo16(pkA1) * inv, hi16(pkA1) * inv };
            f32x4 pnB = { lo16(pkB0) * inv, hi16(pkB0) * inv, lo16(pkB1) * inv, hi16(pkB1) * inv };
            *(f32x4*)(prow + 32 * cc + 4 * g)      = pnA;
            *(f32x4*)(prow + 32 * cc + 16 + 4 * g) = pnB;
        }
        {
            uint2 ua; ua.x = pkA0; ua.y = pkA1;
            uint2 ub; ub.x = pkB0; ub.y = pkB1;
            *(uint2*)&su.plds[w][c][4 * g]      = ua;
            *(uint2*)&su.plds[w][c][16 + 4 * g] = ub;
        }
        bf16x8 pf = *(const bf16x8*)&su.plds[w][c][8 * g];

        // V B-frags: conflict-free scalar column reads
        bf16x8 vfr[4];
        #pragma unroll
        for (int nt = 0; nt < 4; ++nt) {
            bf16x8 f;
            #pragma unroll
            for (int j = 0; j < 8; ++j)
                f[j] = vbufW[nt * NTSTR + (8 * g + j) * VPAD + c];
            vfr[nt] = f;
        }

        __builtin_amdgcn_s_setprio(1);
        #pragma unroll
        for (int nt = 0; nt < 4; ++nt)
            cacc[nt] = __builtin_amdgcn_mfma_f32_16x16x32_bf16(pf, vfr[nt], cacc[nt], 0, 0, 0);
        __builtin_amdgcn_s_setprio(0);
    }

    // =============== ctx partials (scaled by per-row inv) + cross-wave reduce ===============
    #pragma unroll
    for (int nt = 0; nt < 4; ++nt)
        #pragma unroll
        for (int jr = 0; jr < 4; ++jr)
            su.sw[w].ctx[(4 * g + jr) * DIM + nt * 16 + c] = cacc[nt][jr] * invr[jr];
    __syncthreads();
    {
        int e = t * 2;
        float2 a = make_float2(0.f, 0.f);
        #pragma unroll
        for (int i = 0; i < NWAVE; ++i) {
            float2 v = *(const float2*)&su.sw[i].ctx[e];
            a.x += v.x; a.y += v.y;
        }
        *(float2*)(ctx_out + ((size_t)bh * SEQ + q0) * DIM + e) = a;
    }
}

extern "C" void kernel_launch(void* const* d_in, const int* in_sizes, int n_in,
                              void* d_out, int out_size, void* d_ws, size_t ws_size,
                              hipStream_t stream) {
    const float* Q = (const float*)d_in[0];
    const float* K = (const float*)d_in[1];
    const float* V = (const float*)d_in[2];
    const int* mask = (const int*)d_in[3];
    float* ctx  = (float*)d_out;
    float* prob = (float*)d_out + (size_t)4 * 16 * SEQ * DIM;

    dim3 grid(64 * (SEQ / QBLK));   // 8192, divisible by 8 XCDs
    dim3 block(THREADS);
    sdpa_mfma13<<<grid, block, 0, stream>>>(Q, K, V, mask, ctx, prob);
}